// Round 5
// baseline (353.365 us; speedup 1.0000x reference)
//
#include <hip/hip_runtime.h>
#include <math.h>

#define BB 2
#define TT 2048
#define DD 2048
#define HH 16
#define KVHN 4
#define HDIM 128
#define NKV 3072   // packed q|k|v row width

typedef unsigned short u16;
typedef unsigned int u32;
typedef __bf16 bf16x8 __attribute__((ext_vector_type(8)));
typedef float  f32x4  __attribute__((ext_vector_type(4)));

#define AS1 __attribute__((address_space(1)))
#define AS3 __attribute__((address_space(3)))

__device__ __forceinline__ void dma16(const u16* g, u16* l) {
  __builtin_amdgcn_global_load_lds((const AS1 u32*)g, (AS3 u32*)l, 16, 0, 0);
}

__device__ __forceinline__ u16 f2bf(float f) {
  u32 u = __float_as_uint(f);
  u32 r = (u + 0x7FFFu + ((u >> 16) & 1u)) >> 16;
  return (u16)r;
}
__device__ __forceinline__ float bf2f(u32 h) { return __uint_as_float(h << 16); }

__device__ __forceinline__ u32 pack2(float a, float b) {
  union { __bf16 h[2]; u32 u; } cv;
  cv.h[0] = (__bf16)a; cv.h[1] = (__bf16)b;
  return cv.u;
}

// ---------------- fused prep: cast x + transpose/cast all weights ----------
// blocks [0,8192): cast x -> xb
// [8192,12288): Wq tiles; [12288,13312): Wk; [13312,14336): Wv; [14336,18432): Wo
__device__ __forceinline__ void tc_body(const float* __restrict__ W,
                                        u16* __restrict__ WT,
                                        int N, int n0, int k0, int tid,
                                        float (*tile)[33]) {
  const int r = tid >> 3;
  const int c4 = (tid & 7) * 4;
  float4 v = *(const float4*)(W + (size_t)(k0 + r) * N + n0 + c4);
  tile[r][c4 + 0] = v.x; tile[r][c4 + 1] = v.y;
  tile[r][c4 + 2] = v.z; tile[r][c4 + 3] = v.w;
  __syncthreads();
  ushort4 o;
  o.x = f2bf(tile[c4 + 0][r]); o.y = f2bf(tile[c4 + 1][r]);
  o.z = f2bf(tile[c4 + 2][r]); o.w = f2bf(tile[c4 + 3][r]);
  *(ushort4*)(WT + (size_t)(n0 + r) * DD + k0 + c4) = o;
}

__global__ __launch_bounds__(256) void prep(const float* __restrict__ x,
                                            const float* __restrict__ Wq,
                                            const float* __restrict__ Wk,
                                            const float* __restrict__ Wv,
                                            const float* __restrict__ Wo,
                                            u16* __restrict__ xb,
                                            u16* __restrict__ WqkvT,
                                            u16* __restrict__ WoT) {
  __shared__ float tile[32][33];
  const int bid = blockIdx.x;
  const int tid = threadIdx.x;
  if (bid < 8192) {
    size_t i4 = (size_t)bid * 256 + tid;
    float4 v = *(const float4*)(x + i4 * 4);
    ushort4 o;
    o.x = f2bf(v.x); o.y = f2bf(v.y); o.z = f2bf(v.z); o.w = f2bf(v.w);
    *(ushort4*)(xb + i4 * 4) = o;
  } else if (bid < 12288) {
    int idx = bid - 8192;
    tc_body(Wq, WqkvT, DD, (idx & 63) * 32, (idx >> 6) * 32, tid, tile);
  } else if (bid < 13312) {
    int idx = bid - 12288;
    tc_body(Wk, WqkvT + (size_t)2048 * DD, 512, (idx & 15) * 32, (idx >> 4) * 32, tid, tile);
  } else if (bid < 14336) {
    int idx = bid - 13312;
    tc_body(Wv, WqkvT + (size_t)2560 * DD, 512, (idx & 15) * 32, (idx >> 4) * 32, tid, tile);
  } else {
    int idx = bid - 14336;
    tc_body(Wo, WoT, DD, (idx & 63) * 32, (idx >> 6) * 32, tid, tile);
  }
}

// ---------------- m97-style MFMA GEMM: C = A @ BT^T ------------------------
template <int OUT_BF16>
__global__ __launch_bounds__(256) void gemm2(const u16* __restrict__ A,
                                             const u16* __restrict__ BT,
                                             void* __restrict__ Cv,
                                             int N, int K) {
  __shared__ u16 As[128 * 32];
  __shared__ u16 Bs[128 * 32];
  const int t = threadIdx.x;
  const int l = t & 63, w = t >> 6;
  const int lm = l & 15, quad = l >> 4;
  const int wm = w & 1, wn = w >> 1;
  const int m0 = blockIdx.y * 128, n0 = blockIdx.x * 128;
  const int wu = __builtin_amdgcn_readfirstlane(w);

  f32x4 acc[4][4];
  #pragma unroll
  for (int i = 0; i < 4; ++i)
    #pragma unroll
    for (int j = 0; j < 4; ++j) acc[i][j] = (f32x4){0.f, 0.f, 0.f, 0.f};

  for (int k0 = 0; k0 < K; k0 += 32) {
    __syncthreads();
    #pragma unroll
    for (int i = 0; i < 2; ++i) {
      int p0 = (wu * 2 + i) * 64;
      int p = p0 + l;
      int row = p >> 2, c = p & 3;
      dma16(A  + (size_t)(m0 + row) * K + k0 + c * 8, &As[p0 * 8]);
      dma16(BT + (size_t)(n0 + row) * K + k0 + c * 8, &Bs[p0 * 8]);
    }
    __syncthreads();
    bf16x8 a[4], bq[4];
    #pragma unroll
    for (int i = 0; i < 4; ++i)
      a[i] = *(const bf16x8*)&As[(wm * 64 + i * 16 + lm) * 32 + quad * 8];
    #pragma unroll
    for (int j = 0; j < 4; ++j)
      bq[j] = *(const bf16x8*)&Bs[(wn * 64 + j * 16 + lm) * 32 + quad * 8];
    #pragma unroll
    for (int i = 0; i < 4; ++i)
      #pragma unroll
      for (int j = 0; j < 4; ++j)
        acc[i][j] = __builtin_amdgcn_mfma_f32_16x16x32_bf16(a[i], bq[j], acc[i][j], 0, 0, 0);
  }

  #pragma unroll
  for (int i = 0; i < 4; ++i) {
    #pragma unroll
    for (int r = 0; r < 4; ++r) {
      size_t gr = (size_t)(m0 + wm * 64 + i * 16 + quad * 4 + r);
      #pragma unroll
      for (int j = 0; j < 4; ++j) {
        int gc = n0 + wn * 64 + j * 16 + lm;
        if (OUT_BF16) ((u16*)Cv)[gr * N + gc] = f2bf(acc[i][j][r]);
        else          ((float*)Cv)[gr * N + gc] = acc[i][j][r];
      }
    }
  }
}

// ---------------- fused rope (in-place) + V transpose ----------------------
// blocks [0,4096): rope on QKV row; [4096,4608): vtrans tile.
__global__ __launch_bounds__(256) void ropevt(u16* __restrict__ QKV,
                                              u16* __restrict__ Vt) {
  __shared__ u16 tl[64][72];
  const int bid = blockIdx.x;
  if (bid < 4096) {
    const int row = bid;
    const int pos = row & (TT - 1);
    u16* base = QKV + (size_t)row * NKV;
    float e0[5], e1[5];
    #pragma unroll
    for (int i = 0; i < 5; ++i) {
      int item = threadIdx.x + i * 256;
      int h20 = item >> 6, f = item & 63;
      int col = (h20 < 16) ? h20 * 128 : 2048 + (h20 - 16) * 128;
      u32 u = *(const u32*)(base + col + 2 * f);
      e0[i] = bf2f(u & 0xffffu);
      e1[i] = bf2f(u >> 16);
    }
    __syncthreads();
    #pragma unroll
    for (int i = 0; i < 5; ++i) {
      int item = threadIdx.x + i * 256;
      int h20 = item >> 6, f = item & 63;
      int col = (h20 < 16) ? h20 * 128 : 2048 + (h20 - 16) * 128;
      float sc = (h20 < 16) ? 0.08838834764831845f : 1.0f;
      float inv = exp2f((float)f * -0.20762050593046898f);  // 10000^(-f/64)
      float ang = (float)pos * inv;
      float sn = sinf(ang), cs = cosf(ang);
      base[col + f]      = f2bf((e0[i] * cs - e1[i] * sn) * sc);
      base[col + 64 + f] = f2bf((e0[i] * sn + e1[i] * cs) * sc);
    }
  } else {
    const int v = bid - 4096;
    const int t0 = (v & 31) * 64;
    const int y  = (v >> 5) & 7;
    const int b  = v >> 8;
    #pragma unroll
    for (int i = 0; i < 2; ++i) {
      int idx = threadIdx.x + i * 256;
      int r = idx >> 3, c = (idx & 7) * 8;
      *(uint4*)&tl[r][c] =
          *(const uint4*)(QKV + (size_t)(b * TT + t0 + r) * NKV + 2560 + y * 64 + c);
    }
    __syncthreads();
    const int vh = y >> 1;
    #pragma unroll
    for (int i = 0; i < 2; ++i) {
      int idx = threadIdx.x + i * 256;
      int dr = idx >> 3, tc = (idx & 7) * 8;
      u16 tmp[8];
      #pragma unroll
      for (int j = 0; j < 8; ++j) tmp[j] = tl[tc + j][dr];
      int dloc = (y & 1) * 64 + dr;
      *(uint4*)(Vt + (size_t)((b * KVHN + vh) * HDIM + dloc) * TT + t0 + tc) =
          *(const uint4*)tmp;
    }
  }
}

// ---------------- MFMA flash attention v3 (unpaired, 4 blocks/CU) ----------
// Block: 256 thr = 4 waves, one 64-row q-tile; KV-tile 64; single-buffered
// K/V (40 KB LDS total -> 4 blocks/CU); grid 1024 blocks.
__global__ __launch_bounds__(256, 4) void attn3(const u16* __restrict__ QKV,
                                                const u16* __restrict__ Vt,
                                                u16* __restrict__ Ob) {
  __shared__ u16 Ks[64 * 128];     // 16 KB
  __shared__ u16 Vs[128 * 64];     // 16 KB
  __shared__ u16 Pw[4 * 1024];     // 8 KB (per-wave 16x64)
  const int t = threadIdx.x;
  const int l = t & 63, w = t >> 6;
  const int lm = l & 15, quad = l >> 4;
  const int qt = 31 - (int)blockIdx.x;     // heavy blocks first
  const int h = blockIdx.y, b = blockIdx.z;
  const int kvh = h >> 2;
  const int wu = __builtin_amdgcn_readfirstlane(w);
  u16* pwv = &Pw[w * 1024];
  constexpr float L2E = 1.4426950408889634f;

  // Q fragments (B-operand: rows q=lm, contiguous k)
  bf16x8 qf[4];
  {
    size_t r0 = (size_t)(b * TT + qt * 64 + w * 16 + lm) * NKV + h * HDIM;
    #pragma unroll
    for (int ks = 0; ks < 4; ++ks)
      qf[ks] = *(const bf16x8*)(QKV + r0 + ks * 32 + quad * 8);
  }

  f32x4 o[8];
  #pragma unroll
  for (int i = 0; i < 8; ++i) o[i] = (f32x4){0.f, 0.f, 0.f, 0.f};
  float m_ = -1e30f, l_ = 0.f;

  for (int kt = 0; kt <= qt; ++kt) {
    // stage K: 64 kv x 128 d, swizzled chunks (key row&15)
    #pragma unroll
    for (int i = 0; i < 4; ++i) {
      int p0 = (wu * 4 + i) * 64;
      int p = p0 + l;
      int row = p >> 4, cp = p & 15, cl = cp ^ (row & 15);
      dma16(QKV + (size_t)(b * TT + kt * 64 + row) * NKV + 2048 + kvh * HDIM + cl * 8,
            &Ks[p0 * 8]);
    }
    // stage V^T: 128 d x 64 kv, swizzled chunks (key d&7)
    #pragma unroll
    for (int i = 0; i < 4; ++i) {
      int p0 = (wu * 4 + i) * 64;
      int p = p0 + l;
      int d = p >> 3, cp = p & 7, cl = cp ^ (d & 7);
      dma16(Vt + (size_t)((b * KVHN + kvh) * HDIM + d) * TT + kt * 64 + cl * 8,
            &Vs[p0 * 8]);
    }
    __syncthreads();   // DMA drained: K/V visible

    // S^T = K . Q^T  (rows kv, cols q)
    f32x4 s[4];
    #pragma unroll
    for (int mt = 0; mt < 4; ++mt) s[mt] = (f32x4){0.f, 0.f, 0.f, 0.f};
    #pragma unroll
    for (int ks = 0; ks < 4; ++ks)
      #pragma unroll
      for (int mt = 0; mt < 4; ++mt) {
        bf16x8 kb = *(const bf16x8*)&Ks[(mt * 16 + lm) * 128 + (((ks * 4 + quad) ^ lm) * 8)];
        s[mt] = __builtin_amdgcn_mfma_f32_16x16x32_bf16(kb, qf[ks], s[mt], 0, 0, 0);
      }

    // causal mask on diagonal tile
    if (kt == qt) {
      #pragma unroll
      for (int mt = 0; mt < 4; ++mt)
        #pragma unroll
        for (int r = 0; r < 4; ++r) {
          int kv = kt * 64 + mt * 16 + quad * 4 + r;
          if (kv > qt * 64 + w * 16 + lm) s[mt][r] = -1e30f;
        }
    }

    // online softmax (per q-col lm; reduce in-lane 16 + cross-quad shfl x2)
    float mx = -1e30f;
    #pragma unroll
    for (int mt = 0; mt < 4; ++mt)
      #pragma unroll
      for (int r = 0; r < 4; ++r) mx = fmaxf(mx, s[mt][r]);
    mx = fmaxf(mx, __shfl_xor(mx, 16));
    mx = fmaxf(mx, __shfl_xor(mx, 32));
    float mn = fmaxf(m_, mx);
    float al = exp2f((m_ - mn) * L2E);
    m_ = mn;
    float sum = 0.f;
    #pragma unroll
    for (int mt = 0; mt < 4; ++mt)
      #pragma unroll
      for (int r = 0; r < 4; ++r) {
        float pv = exp2f((s[mt][r] - mn) * L2E);
        s[mt][r] = pv;
        sum += pv;
      }
    sum += __shfl_xor(sum, 16);
    sum += __shfl_xor(sum, 32);
    l_ = l_ * al + sum;

    // P -> LDS (b64 swizzled, per-wave region, P[q][kv] chunks ^ (lm&7))
    #pragma unroll
    for (int mt = 0; mt < 4; ++mt) {
      u32 p01 = pack2(s[mt][0], s[mt][1]);
      u32 p23 = pack2(s[mt][2], s[mt][3]);
      int phys = (mt * 2 + (quad >> 1)) ^ (lm & 7);
      int addr = lm * 64 + phys * 8 + (quad & 1) * 4;
      uint2 uv; uv.x = p01; uv.y = p23;
      *(uint2*)&pwv[addr] = uv;
    }
    // O^T rescale
    if (__any(al < 1.0f)) {
      #pragma unroll
      for (int mt2 = 0; mt2 < 8; ++mt2)
        #pragma unroll
        for (int r = 0; r < 4; ++r) o[mt2][r] *= al;
    }

    // O^T += V^T . P^T
    #pragma unroll
    for (int ks2 = 0; ks2 < 2; ++ks2) {
      int coff = ((ks2 * 4 + quad) ^ (lm & 7)) * 8;
      bf16x8 pb = *(const bf16x8*)&pwv[lm * 64 + coff];
      #pragma unroll
      for (int mt2 = 0; mt2 < 8; ++mt2) {
        bf16x8 vb = *(const bf16x8*)&Vs[(mt2 * 16 + lm) * 64 + coff];
        o[mt2] = __builtin_amdgcn_mfma_f32_16x16x32_bf16(vb, pb, o[mt2], 0, 0, 0);
      }
    }
    __syncthreads();   // all reads done before next stage overwrites
  }

  // epilogue: O^T -> LDS transpose -> coalesced stores, in two 64-dim halves
  float inv = 1.f / l_;
  #pragma unroll
  for (int half = 0; half < 2; ++half) {
    #pragma unroll
    for (int m2 = 0; m2 < 4; ++m2) {
      int mt2 = half * 4 + m2;
      u32 a0 = pack2(o[mt2][0] * inv, o[mt2][1] * inv);
      u32 a1 = pack2(o[mt2][2] * inv, o[mt2][3] * inv);
      int phys = (m2 * 2 + (quad >> 1)) ^ (lm & 7);
      int addr = lm * 64 + phys * 8 + (quad & 1) * 4;
      uint2 uv; uv.x = a0; uv.y = a1;
      *(uint2*)&pwv[addr] = uv;
    }
    // 16 q-rows x 8 chunks (64 dims) = 128 chunks -> 2 iters
    #pragma unroll
    for (int i = 0; i < 2; ++i) {
      int p = i * 64 + l;
      int row = p >> 3, cl = p & 7;
      int cph = cl ^ (row & 7);
      uint4 val = *(const uint4*)&pwv[row * 64 + cph * 8];
      *(uint4*)(Ob + (size_t)(b * TT + qt * 64 + w * 16 + row) * DD +
                h * HDIM + half * 64 + cl * 8) = val;
    }
  }
}

extern "C" void kernel_launch(void* const* d_in, const int* in_sizes, int n_in,
                              void* d_out, int out_size, void* d_ws, size_t ws_size,
                              hipStream_t stream) {
  const float* x  = (const float*)d_in[0];
  const float* Wq = (const float*)d_in[1];
  const float* Wk = (const float*)d_in[2];
  const float* Wv = (const float*)d_in[3];
  const float* Wo = (const float*)d_in[4];
  float* out = (float*)d_out;

  // ws (u16 elems): xb @0 (8M, -> Ob) | WqkvT @8M (6M, -> Vt) | WoT @14.68M (4M)
  u16* xb    = (u16*)d_ws;
  u16* WqkvT = xb + 8388608;
  u16* WoT   = xb + 14680064;
  u16* Vt    = WqkvT;               // alias, live after QKV GEMM
  u16* Ob    = xb;                  // alias, live after QKV GEMM
  u16* QKVb  = (u16*)d_out;         // bf16 [4096][3072] in the 32MB out buffer

  dim3 blk(256);
  prep<<<18432, blk, 0, stream>>>(x, Wq, Wk, Wv, Wo, xb, WqkvT, WoT);
  gemm2<1><<<dim3(NKV / 128, 32), blk, 0, stream>>>(xb, WqkvT, QKVb, NKV, DD);
  ropevt<<<4608, blk, 0, stream>>>(QKVb, Vt);
  attn3<<<dim3(32, HH, BB), blk, 0, stream>>>(QKVb, Vt, Ob);
  gemm2<0><<<dim3(DD / 128, 32), blk, 0, stream>>>(Ob, WoT, out, DD, DD);
}